// Round 8
// baseline (6498.425 us; speedup 1.0000x reference)
//
#include <hip/hip_runtime.h>
#include <hip/hip_bf16.h>
#include <stdint.h>

// EncoderLayer, MI355X. B=8 L=1024 DM=512 H=8 DK=64 DV=512.
// Round 8: round-7 passing base with k_sattn moved to register-resident S
// (no 128KB S LDS; 512 thr/block, wave-owned q-rows, K from global, Q via
// LDS broadcast). Everything else byte-identical to round 7.

using bf16 = __hip_bfloat16;
typedef float f32x4 __attribute__((ext_vector_type(4)));
typedef short s16x4 __attribute__((ext_vector_type(4)));
typedef short s16x8 __attribute__((ext_vector_type(8)));

#define DEV static __device__ __forceinline__

DEV float us2f(unsigned short u) { union { uint32_t i; float f; } x; x.i = ((uint32_t)u) << 16; return x.f; }
DEV float s2f(short s) { return us2f((unsigned short)s); }
DEV unsigned short f2bfu(float x) { return __builtin_bit_cast(unsigned short, __float2bfloat16(x)); }
DEV float bf2f(bf16 x) { return __bfloat162float(x); }
DEV bf16 f2bf(float x) { return __float2bfloat16(x); }

// D = A(16x32)*B(32x16)+C. A: lane l holds A[l&15][8*(l>>4)+j]; B: lane l holds
// B[8*(l>>4)+j][l&15]; C/D: col=lane&15, row=4*(lane>>4)+reg (m89-verified).
DEV void mfma_bf16(f32x4& c, s16x8 a, s16x8 b) {
    asm("v_mfma_f32_16x16x32_bf16 %0, %1, %2, %0" : "+v"(c) : "v"(a), "v"(b));
}

// split 8 consecutive f32 into bf16 hi + lo
DEV void cvt8(const float* p, s16x8& h, s16x8& l) {
    #pragma unroll
    for (int j = 0; j < 8; ++j) {
        const float v = p[j];
        const unsigned short hu = f2bfu(v);
        h[j] = (short)hu;
        l[j] = (short)f2bfu(v - us2f(hu));
    }
}
DEV void cvt8hi(const float* p, s16x8& h) {
    #pragma unroll
    for (int j = 0; j < 8; ++j) h[j] = (short)f2bfu(p[j]);
}

// ---------------- lengths extraction (robust to u8/i32/f32 mask encodings) ------------
__global__ void k_lengths(const unsigned char* __restrict__ mask, int* __restrict__ lens)
{
    __shared__ int flags[2];
    __shared__ int cnt[8];
    const int t = threadIdx.x;  // 256 threads
    if (t < 2) flags[t] = 0;
    if (t < 8) cnt[t] = 0;
    __syncthreads();
    int f0 = 0, f1 = 0;
    for (int i = t; i < 8192; i += 256) {
        unsigned char v = mask[i];
        if ((i & 3) != 0 && v != 0) f0 = 1;
        if ((i & 3) == 3 && v == 0x3F) f1 = 1;   // f32 1.0f high byte
    }
    if (f0) atomicOr(&flags[0], 1);
    if (f1) atomicOr(&flags[1], 1);
    __syncthreads();
    const int mode = flags[1] ? 2 : (flags[0] ? 0 : 1); // 0=u8, 1=i32, 2=f32
    const int b = t >> 5, lane32 = t & 31;
    int padc = 0;
    for (int j = lane32; j < 1024; j += 32) {
        const int idx = b * 1024 + j;
        bool pad;
        if (mode == 0)      pad = mask[idx] != 0;
        else if (mode == 1) pad = ((const int*)mask)[idx] != 0;
        else                pad = ((const float*)mask)[idx] != 0.0f;
        padc += pad ? 1 : 0;
    }
    atomicAdd(&cnt[b], padc);
    __syncthreads();
    if (t < 8) {
        const int len = 1024 - cnt[t];
        lens[t] = len;                     // actual length
        lens[8 + t] = (len + 31) >> 5;     // 32-granular steps
        lens[16 + t] = (len + 7) >> 3;
    }
}

// ---------------- unified MFMA GEMM: C = A * B^T, 128x128 tile, BK=32 ------------------
// MODE 0: Q/K proj (A=enc f32, Bt=w f32 [512][512]) -> f32 scatter [h][b][l][dk] + bias
// MODE 1: V proj   (A=enc f32 hi-only, Bt=wv f32 split) -> Vt bf16 [h][b][dv][l] + bias
// MODE 2: PV       (z=batch: A=P_z f32 [1024][1024], Bt=Vt_(aux,z) bf16, nk len-capped)
//                  -> O bf16 [aux][z][l][dv]
// MODE 3: gate     (z=head: A=O_z bf16, Bt=wg_z f32) -> G bf16 + bias
// MODE 4: fc       (A=comb f32, Bt=wfc f32) -> f32 out + bias + resid + pad-mask
template<int MODE>
__launch_bounds__(256)
__global__ void mgemm(const void* __restrict__ Abase, const void* __restrict__ Bbase,
                      void* __restrict__ Cbase, const float* __restrict__ bias,
                      const float* __restrict__ resid, const int* __restrict__ lens,
                      int ntn, int aux)
{
    constexpr bool A_BF = (MODE == 3);                      // A is bf16-native
    constexpr bool B_BF = (MODE == 2);                      // B is bf16-native
    constexpr bool A_SP = (MODE == 0 || MODE == 4);         // split A (hi+lo)
    constexpr bool B_SP = !B_BF;                            // split B (hi+lo)
    constexpr int LS = 40;                                  // LDS row stride (elems)

    __shared__ bf16 sAh[128 * LS];
    __shared__ bf16 sAl[A_SP ? 128 * LS : 8];
    __shared__ bf16 sBh[128 * LS];
    __shared__ bf16 sBl[B_SP ? 128 * LS : 8];

    const int bx = blockIdx.x, z = blockIdx.y;
    const int mt = bx / ntn, nt = bx % ntn;
    const int m0 = mt * 128, n0 = nt * 128;
    const int tid = threadIdx.x;
    const int lane = tid & 63, w = tid >> 6;
    const int l16 = lane & 15, l4 = lane >> 4;
    const int wm = w >> 1, wn = w & 1;

    const char* A = (const char*)Abase;
    const char* Bt = (const char*)Bbase;
    int lda = 512, ldb = 512, nkb = 16;
    if (MODE == 2) {
        A  += (size_t)z * 1048576 * 4;   // P_z (f32 1024x1024)
        Bt += (size_t)z * 524288 * 2;    // Vt_(aux,z) (bf16 512x1024)
        lda = 1024; ldb = 1024;
        nkb = lens[8 + z];
    }
    if (MODE == 3) {
        A  += (size_t)z * 4194304 * 2;   // O_z (bf16 8192x512)
        Bt += (size_t)z * 262144 * 4;    // wg_z (f32 512x512)
    }

    f32x4 acc[4][4];
    #pragma unroll
    for (int i = 0; i < 4; ++i)
        #pragma unroll
        for (int j = 0; j < 4; ++j) acc[i][j] = (f32x4){0.f, 0.f, 0.f, 0.f};

    const int sr = tid >> 1, sc = (tid & 1) * 16;   // staging: row, col-half

    for (int kt = 0; kt < nkb; ++kt) {
        const int kb = kt * 32;
        __syncthreads();
        // ---- stage A tile (128 x 32) ----
        if constexpr (A_BF) {
            const bf16* p = (const bf16*)A + (size_t)(m0 + sr) * lda + kb + sc;
            *(s16x8*)&sAh[sr * LS + sc]     = *(const s16x8*)p;
            *(s16x8*)&sAh[sr * LS + sc + 8] = *(const s16x8*)(p + 8);
        } else {
            const float* p = (const float*)A + (size_t)(m0 + sr) * lda + kb + sc;
            s16x8 h0, h1;
            if constexpr (A_SP) {
                s16x8 l0, l1;
                cvt8(p, h0, l0); cvt8(p + 8, h1, l1);
                *(s16x8*)&sAl[sr * LS + sc]     = l0;
                *(s16x8*)&sAl[sr * LS + sc + 8] = l1;
            } else {
                cvt8hi(p, h0); cvt8hi(p + 8, h1);
            }
            *(s16x8*)&sAh[sr * LS + sc]     = h0;
            *(s16x8*)&sAh[sr * LS + sc + 8] = h1;
        }
        // ---- stage B tile (128 x 32) ----
        if constexpr (B_BF) {
            const bf16* p = (const bf16*)Bt + (size_t)(n0 + sr) * ldb + kb + sc;
            *(s16x8*)&sBh[sr * LS + sc]     = *(const s16x8*)p;
            *(s16x8*)&sBh[sr * LS + sc + 8] = *(const s16x8*)(p + 8);
        } else {
            const float* p = (const float*)Bt + (size_t)(n0 + sr) * ldb + kb + sc;
            s16x8 h0, h1, l0, l1;
            cvt8(p, h0, l0); cvt8(p + 8, h1, l1);
            *(s16x8*)&sBh[sr * LS + sc]     = h0;
            *(s16x8*)&sBh[sr * LS + sc + 8] = h1;
            *(s16x8*)&sBl[sr * LS + sc]     = l0;
            *(s16x8*)&sBl[sr * LS + sc + 8] = l1;
        }
        __syncthreads();

        // ---- fragments + MFMA ----
        s16x8 ah[4], al[4], bh[4], bl[4];
        #pragma unroll
        for (int i = 0; i < 4; ++i) {
            const int ra = (wm * 64 + i * 16 + l16) * LS + l4 * 8;
            const int rb = (wn * 64 + i * 16 + l16) * LS + l4 * 8;
            ah[i] = *(const s16x8*)&sAh[ra];
            if constexpr (A_SP) al[i] = *(const s16x8*)&sAl[ra];
            bh[i] = *(const s16x8*)&sBh[rb];
            if constexpr (B_SP) bl[i] = *(const s16x8*)&sBl[rb];
        }
        #pragma unroll
        for (int mi = 0; mi < 4; ++mi)
            #pragma unroll
            for (int ni = 0; ni < 4; ++ni) {
                mfma_bf16(acc[mi][ni], ah[mi], bh[ni]);
                if constexpr (B_SP) mfma_bf16(acc[mi][ni], ah[mi], bl[ni]);
                if constexpr (A_SP) mfma_bf16(acc[mi][ni], al[mi], bh[ni]);
            }
    }

    // ---- epilogues (C frag: row = 4*l4 + r, col = l16) ----
    if constexpr (MODE == 0) {
        float* Q = (float*)Cbase;
        #pragma unroll
        for (int ni = 0; ni < 4; ++ni) {
            const int gn = n0 + wn * 64 + ni * 16 + l16;
            const float bs = bias[gn];
            const int h = gn >> 6, dk = gn & 63;
            #pragma unroll
            for (int mi = 0; mi < 4; ++mi) {
                const int gm0 = m0 + wm * 64 + mi * 16 + l4 * 4;
                const int b = gm0 >> 10, l0 = gm0 & 1023;
                float* dst = Q + (((size_t)(h * 8 + b)) * 1024 + l0) * 64 + dk;
                #pragma unroll
                for (int r = 0; r < 4; ++r) dst[(size_t)r * 64] = acc[mi][ni][r] + bs;
            }
        }
    } else if constexpr (MODE == 1) {
        bf16* Vt = (bf16*)Cbase;
        #pragma unroll
        for (int ni = 0; ni < 4; ++ni) {
            const int gn = n0 + wn * 64 + ni * 16 + l16;
            const float bs = bias[gn];
            const int h = gn >> 9, dv = gn & 511;
            #pragma unroll
            for (int mi = 0; mi < 4; ++mi) {
                const int gm0 = m0 + wm * 64 + mi * 16 + l4 * 4;
                const int b = gm0 >> 10, l0 = gm0 & 1023;
                ushort4 t;
                t.x = f2bfu(acc[mi][ni][0] + bs);
                t.y = f2bfu(acc[mi][ni][1] + bs);
                t.z = f2bfu(acc[mi][ni][2] + bs);
                t.w = f2bfu(acc[mi][ni][3] + bs);
                *(ushort4*)(Vt + ((size_t)(h * 8 + b) * 512 + dv) * 1024 + l0) = t;
            }
        }
    } else if constexpr (MODE == 2) {
        bf16* O = (bf16*)Cbase + (size_t)(aux * 8 + z) * 524288;
        #pragma unroll
        for (int mi = 0; mi < 4; ++mi) {
            const int gm0 = m0 + wm * 64 + mi * 16 + l4 * 4;
            #pragma unroll
            for (int ni = 0; ni < 4; ++ni) {
                const int gn = n0 + wn * 64 + ni * 16 + l16;
                #pragma unroll
                for (int r = 0; r < 4; ++r)
                    O[(size_t)(gm0 + r) * 512 + gn] = f2bf(acc[mi][ni][r]);
            }
        }
    } else if constexpr (MODE == 3) {
        bf16* G = (bf16*)Cbase + (size_t)z * 4194304;
        #pragma unroll
        for (int ni = 0; ni < 4; ++ni) {
            const int gn = n0 + wn * 64 + ni * 16 + l16;
            const float bs = bias[z * 512 + gn];
            #pragma unroll
            for (int mi = 0; mi < 4; ++mi) {
                const int gm0 = m0 + wm * 64 + mi * 16 + l4 * 4;
                #pragma unroll
                for (int r = 0; r < 4; ++r)
                    G[(size_t)(gm0 + r) * 512 + gn] = f2bf(acc[mi][ni][r] + bs);
            }
        }
    } else {
        float* Out = (float*)Cbase;
        #pragma unroll
        for (int mi = 0; mi < 4; ++mi) {
            const int gm0 = m0 + wm * 64 + mi * 16 + l4 * 4;
            const int len = lens[gm0 >> 10];
            #pragma unroll
            for (int ni = 0; ni < 4; ++ni) {
                const int gn = n0 + wn * 64 + ni * 16 + l16;
                const float bs = bias[gn];
                #pragma unroll
                for (int r = 0; r < 4; ++r) {
                    const int gm = gm0 + r;
                    const bool dead = (gm & 1023) >= len;
                    Out[(size_t)gm * 512 + gn] =
                        dead ? 0.f : acc[mi][ni][r] + bs + resid[(size_t)gm * 512 + gn];
                }
            }
        }
    }
}

// ---------------- register-S: S = QK^T/8, masked softmax, P f32 (zero-padded) ----------
// Block = (qb: 32 q-rows, z: batch), 512 threads = 8 waves; wave w owns q-rows
// [4w,4w+4); lane holds S for k = lane + 64*i, i in [0,16). No S LDS.
__launch_bounds__(512)
__global__ void k_sattn_reg(const float* __restrict__ Qf, const float* __restrict__ Kf,
                            float* __restrict__ P, const int* __restrict__ lens, int head)
{
    __shared__ float sQ[32][64];
    const int qb = blockIdx.x, z = blockIdx.y;      // z = batch
    const int hb = head * 8 + z;
    const int tid = threadIdx.x;

    {   // stage Q tile (32 x 64 f32): 512 threads x 4 floats
        const int r = tid >> 4, c0 = (tid & 15) * 4;
        *(f32x4*)&sQ[r][c0] =
            *(const f32x4*)&Qf[((size_t)hb * 1024 + (size_t)qb * 32 + r) * 64 + c0];
    }
    __syncthreads();

    const int w = tid >> 6, lane = tid & 63;
    const float* Kbase = Kf + (size_t)hb * 65536;
    const float* qp = &sQ[w * 4][0];                // wave-uniform row base

    float s[4][16];                                  // S values, fully static idx
    #pragma unroll
    for (int i = 0; i < 16; ++i) {
        const float* kp = Kbase + (size_t)(i * 64 + lane) * 64;
        // first 32 dims
        f32x4 kr[8];
        #pragma unroll
        for (int j = 0; j < 8; ++j) kr[j] = *(const f32x4*)(kp + j * 4);
        float a0 = 0.f, a1 = 0.f, a2 = 0.f, a3 = 0.f;
        #pragma unroll
        for (int j = 0; j < 8; ++j) {
            const f32x4 q0 = *(const f32x4*)(qp + 0 * 64 + j * 4);
            const f32x4 q1 = *(const f32x4*)(qp + 1 * 64 + j * 4);
            const f32x4 q2 = *(const f32x4*)(qp + 2 * 64 + j * 4);
            const f32x4 q3 = *(const f32x4*)(qp + 3 * 64 + j * 4);
            a0 += q0[0]*kr[j][0] + q0[1]*kr[j][1] + q0[2]*kr[j][2] + q0[3]*kr[j][3];
            a1 += q1[0]*kr[j][0] + q1[1]*kr[j][1] + q1[2]*kr[j][2] + q1[3]*kr[j][3];
            a2 += q2[0]*kr[j][0] + q2[1]*kr[j][1] + q2[2]*kr[j][2] + q2[3]*kr[j][3];
            a3 += q3[0]*kr[j][0] + q3[1]*kr[j][1] + q3[2]*kr[j][2] + q3[3]*kr[j][3];
        }
        // second 32 dims (reuse kr regs)
        #pragma unroll
        for (int j = 0; j < 8; ++j) kr[j] = *(const f32x4*)(kp + 32 + j * 4);
        #pragma unroll
        for (int j = 0; j < 8; ++j) {
            const f32x4 q0 = *(const f32x4*)(qp + 0 * 64 + 32 + j * 4);
            const f32x4 q1 = *(const f32x4*)(qp + 1 * 64 + 32 + j * 4);
            const f32x4 q2 = *(const f32x4*)(qp + 2 * 64 + 32 + j * 4);
            const f32x4 q3 = *(const f32x4*)(qp + 3 * 64 + 32 + j * 4);
            a0 += q0[0]*kr[j][0] + q0[1]*kr[j][1] + q0[2]*kr[j][2] + q0[3]*kr[j][3];
            a1 += q1[0]*kr[j][0] + q1[1]*kr[j][1] + q1[2]*kr[j][2] + q1[3]*kr[j][3];
            a2 += q2[0]*kr[j][0] + q2[1]*kr[j][1] + q2[2]*kr[j][2] + q2[3]*kr[j][3];
            a3 += q3[0]*kr[j][0] + q3[1]*kr[j][1] + q3[2]*kr[j][2] + q3[3]*kr[j][3];
        }
        s[0][i] = a0 * 0.125f;
        s[1][i] = a1 * 0.125f;
        s[2][i] = a2 * 0.125f;
        s[3][i] = a3 * 0.125f;
    }

    const int len = lens[z], lenpad = lens[8 + z] * 32;
    #pragma unroll
    for (int q = 0; q < 4; ++q) {
        float mx = -3.0e38f;
        #pragma unroll
        for (int i = 0; i < 16; ++i)
            if (i * 64 + lane < len) mx = fmaxf(mx, s[q][i]);
        #pragma unroll
        for (int off = 32; off; off >>= 1) mx = fmaxf(mx, __shfl_xor(mx, off));
        float sum = 0.f;
        #pragma unroll
        for (int i = 0; i < 16; ++i) {
            const float e = (i * 64 + lane < len) ? __expf(s[q][i] - mx) : 0.f;
            s[q][i] = e;
            sum += e;
        }
        #pragma unroll
        for (int off = 32; off; off >>= 1) sum += __shfl_xor(sum, off);
        const float rinv = 1.0f / sum;
        float* Pr = P + ((size_t)z * 1024 + (size_t)qb * 32 + w * 4 + q) * 1024;
        #pragma unroll
        for (int i = 0; i < 16; ++i) {
            const int k = i * 64 + lane;
            if (k < lenpad) Pr[k] = s[q][i] * rinv;
        }
    }
}

// ---------------- head-softmax gate combine: comb = sum_h softmax_h(G) * O -------------
__launch_bounds__(512)
__global__ void k_combine_f32(const bf16* __restrict__ G, const bf16* __restrict__ O,
                              float* __restrict__ comb)
{
    const size_t row = blockIdx.x;
    const int e = threadIdx.x;
    const size_t idx = row * 512 + e;
    float g[8];
    #pragma unroll
    for (int h = 0; h < 8; ++h) g[h] = bf2f(G[(size_t)h * 4194304 + idx]);
    float mx = g[0];
    #pragma unroll
    for (int h = 1; h < 8; ++h) mx = fmaxf(mx, g[h]);
    float s = 0.f, c = 0.f;
    #pragma unroll
    for (int h = 0; h < 8; ++h) {
        const float p = __expf(g[h] - mx);
        s += p;
        c += p * bf2f(O[(size_t)h * 4194304 + idx]);
    }
    comb[idx] = c / s;
}

__global__ void k_sentinel(float* out, int n) {
    const int i = blockIdx.x * 256 + threadIdx.x;
    if (i < n) out[i] = 12345.0f;
}

// ---------------------------------------------------------------------------------------
extern "C" void kernel_launch(void* const* d_in, const int* in_sizes, int n_in,
                              void* d_out, int out_size, void* d_ws, size_t ws_size,
                              hipStream_t stream)
{
    const float* enc = (const float*)d_in[0];
    const unsigned char* npm = (const unsigned char*)d_in[1];
    const float* wq  = (const float*)d_in[3];
    const float* bq  = (const float*)d_in[4];
    const float* wk  = (const float*)d_in[5];
    const float* bk  = (const float*)d_in[6];
    const float* wv  = (const float*)d_in[7];
    const float* bv  = (const float*)d_in[8];
    const float* wg  = (const float*)d_in[9];
    const float* bg  = (const float*)d_in[10];
    const float* wfc = (const float*)d_in[11];
    const float* bfc = (const float*)d_in[12];

    char* ws = (char*)d_ws;
    size_t o = 0;
    auto take = [&](size_t bytes) { char* p = ws + o; o += (bytes + 255) & ~(size_t)255; return p; };
    int*   lens = (int*)take(128);
    float* Qf   = (float*)take((size_t)4194304 * 4);   // [h][b][l][dk] f32
    float* Kf   = (float*)take((size_t)4194304 * 4);   // [h][b][l][dk] f32
    bf16*  Vt   = (bf16*)take((size_t)33554432 * 2);   // [h][b][dv][l] bf16; reused as G
    bf16*  Ob   = (bf16*)take((size_t)33554432 * 2);   // [h][b][l][dv] bf16
    float* Pf   = (float*)take((size_t)8388608 * 4);   // one head: [b][q][k] f32
    float* comb = (float*)take((size_t)4194304 * 4);   // [b,l][dv] f32
    bf16*  Gb   = Vt;

    if (ws_size < o) {
        k_sentinel<<<dim3((out_size + 255) / 256), 256, 0, stream>>>((float*)d_out, out_size);
        return;
    }

    k_lengths<<<1, 256, 0, stream>>>(npm, lens);

    // Q, K projections (MFMA, split-bf16 3-term); V projection (2-term)
    mgemm<0><<<dim3(64 * 4, 1), 256, 0, stream>>>(enc, wq, Qf, bq, nullptr, lens, 4, 0);
    mgemm<0><<<dim3(64 * 4, 1), 256, 0, stream>>>(enc, wk, Kf, bk, nullptr, lens, 4, 0);
    mgemm<1><<<dim3(64 * 32, 1), 256, 0, stream>>>(enc, wv, Vt, bv, nullptr, lens, 32, 0);

    // attention per head: register-S softmax -> P, then MFMA PV -> O
    for (int g = 0; g < 8; ++g) {
        k_sattn_reg<<<dim3(32, 8), 512, 0, stream>>>(Qf, Kf, Pf, lens, g);
        mgemm<2><<<dim3(8 * 4, 8), 256, 0, stream>>>(Pf, Vt + (size_t)g * 4194304, Ob,
                                                     nullptr, nullptr, lens, 4, g);
    }

    // gate GEMM per head (MFMA, A bf16-native, B split 2-term)
    mgemm<3><<<dim3(64 * 4, 8), 256, 0, stream>>>(Ob, wg, Gb, bg, nullptr, lens, 4, 0);

    // head softmax + weighted combine
    k_combine_f32<<<dim3(8192), 512, 0, stream>>>(Gb, Ob, comb);

    // FC + bias + residual + pad-mask -> f32 out
    mgemm<4><<<dim3(64 * 4, 1), 256, 0, stream>>>(comb, wfc, d_out, bfc, enc, lens, 4, 0);
}

// Round 9
// 1010.109 us; speedup vs baseline: 6.4334x; 6.4334x over previous
//
#include <hip/hip_runtime.h>
#include <hip/hip_bf16.h>
#include <stdint.h>

// EncoderLayer, MI355X. B=8 L=1024 DM=512 H=8 DK=64 DV=512.
// Round 9: round-7 passing base; k_sattn = register-S softmax (round-8 tail,
// verified) + LDS-staged XOR-swizzled K chunks (spill-free, ~105 VGPR).
// P stored bf16; PV (MODE 2) reads bf16 A natively.

using bf16 = __hip_bfloat16;
typedef float f32x4 __attribute__((ext_vector_type(4)));
typedef short s16x4 __attribute__((ext_vector_type(4)));
typedef short s16x8 __attribute__((ext_vector_type(8)));

#define DEV static __device__ __forceinline__

DEV float us2f(unsigned short u) { union { uint32_t i; float f; } x; x.i = ((uint32_t)u) << 16; return x.f; }
DEV float s2f(short s) { return us2f((unsigned short)s); }
DEV unsigned short f2bfu(float x) { return __builtin_bit_cast(unsigned short, __float2bfloat16(x)); }
DEV float bf2f(bf16 x) { return __bfloat162float(x); }
DEV bf16 f2bf(float x) { return __float2bfloat16(x); }

// D = A(16x32)*B(32x16)+C. A: lane l holds A[l&15][8*(l>>4)+j]; B: lane l holds
// B[8*(l>>4)+j][l&15]; C/D: col=lane&15, row=4*(lane>>4)+reg (m89-verified).
DEV void mfma_bf16(f32x4& c, s16x8 a, s16x8 b) {
    asm("v_mfma_f32_16x16x32_bf16 %0, %1, %2, %0" : "+v"(c) : "v"(a), "v"(b));
}

// split 8 consecutive f32 into bf16 hi + lo
DEV void cvt8(const float* p, s16x8& h, s16x8& l) {
    #pragma unroll
    for (int j = 0; j < 8; ++j) {
        const float v = p[j];
        const unsigned short hu = f2bfu(v);
        h[j] = (short)hu;
        l[j] = (short)f2bfu(v - us2f(hu));
    }
}
DEV void cvt8hi(const float* p, s16x8& h) {
    #pragma unroll
    for (int j = 0; j < 8; ++j) h[j] = (short)f2bfu(p[j]);
}

// ---------------- lengths extraction (robust to u8/i32/f32 mask encodings) ------------
__global__ void k_lengths(const unsigned char* __restrict__ mask, int* __restrict__ lens)
{
    __shared__ int flags[2];
    __shared__ int cnt[8];
    const int t = threadIdx.x;  // 256 threads
    if (t < 2) flags[t] = 0;
    if (t < 8) cnt[t] = 0;
    __syncthreads();
    int f0 = 0, f1 = 0;
    for (int i = t; i < 8192; i += 256) {
        unsigned char v = mask[i];
        if ((i & 3) != 0 && v != 0) f0 = 1;
        if ((i & 3) == 3 && v == 0x3F) f1 = 1;   // f32 1.0f high byte
    }
    if (f0) atomicOr(&flags[0], 1);
    if (f1) atomicOr(&flags[1], 1);
    __syncthreads();
    const int mode = flags[1] ? 2 : (flags[0] ? 0 : 1); // 0=u8, 1=i32, 2=f32
    const int b = t >> 5, lane32 = t & 31;
    int padc = 0;
    for (int j = lane32; j < 1024; j += 32) {
        const int idx = b * 1024 + j;
        bool pad;
        if (mode == 0)      pad = mask[idx] != 0;
        else if (mode == 1) pad = ((const int*)mask)[idx] != 0;
        else                pad = ((const float*)mask)[idx] != 0.0f;
        padc += pad ? 1 : 0;
    }
    atomicAdd(&cnt[b], padc);
    __syncthreads();
    if (t < 8) {
        const int len = 1024 - cnt[t];
        lens[t] = len;                     // actual length
        lens[8 + t] = (len + 31) >> 5;     // 32-granular steps
        lens[16 + t] = (len + 7) >> 3;
    }
}

// ---------------- unified MFMA GEMM: C = A * B^T, 128x128 tile, BK=32 ------------------
// MODE 0: Q/K proj (A=enc f32, Bt=w f32 [512][512]) -> f32 scatter [h][b][l][dk] + bias
// MODE 1: V proj   (A=enc f32 hi-only, Bt=wv f32 split) -> Vt bf16 [h][b][dv][l] + bias
// MODE 2: PV       (z=batch: A=P_z bf16 [1024][1024], Bt=Vt_(aux,z) bf16, nk len-capped)
//                  -> O bf16 [aux][z][l][dv]
// MODE 3: gate     (z=head: A=O_z bf16, Bt=wg_z f32) -> G bf16 + bias
// MODE 4: fc       (A=comb f32, Bt=wfc f32) -> f32 out + bias + resid + pad-mask
template<int MODE>
__launch_bounds__(256)
__global__ void mgemm(const void* __restrict__ Abase, const void* __restrict__ Bbase,
                      void* __restrict__ Cbase, const float* __restrict__ bias,
                      const float* __restrict__ resid, const int* __restrict__ lens,
                      int ntn, int aux)
{
    constexpr bool A_BF = (MODE == 2 || MODE == 3);         // A is bf16-native
    constexpr bool B_BF = (MODE == 2);                      // B is bf16-native
    constexpr bool A_SP = (MODE == 0 || MODE == 4);         // split A (hi+lo)
    constexpr bool B_SP = !B_BF;                            // split B (hi+lo)
    constexpr int LS = 40;                                  // LDS row stride (elems)

    __shared__ bf16 sAh[128 * LS];
    __shared__ bf16 sAl[A_SP ? 128 * LS : 8];
    __shared__ bf16 sBh[128 * LS];
    __shared__ bf16 sBl[B_SP ? 128 * LS : 8];

    const int bx = blockIdx.x, z = blockIdx.y;
    const int mt = bx / ntn, nt = bx % ntn;
    const int m0 = mt * 128, n0 = nt * 128;
    const int tid = threadIdx.x;
    const int lane = tid & 63, w = tid >> 6;
    const int l16 = lane & 15, l4 = lane >> 4;
    const int wm = w >> 1, wn = w & 1;

    const char* A = (const char*)Abase;
    const char* Bt = (const char*)Bbase;
    int lda = 512, ldb = 512, nkb = 16;
    if (MODE == 2) {
        A  += (size_t)z * 1048576 * 2;   // P_z (bf16 1024x1024)
        Bt += (size_t)z * 524288 * 2;    // Vt_(aux,z) (bf16 512x1024)
        lda = 1024; ldb = 1024;
        nkb = lens[8 + z];
    }
    if (MODE == 3) {
        A  += (size_t)z * 4194304 * 2;   // O_z (bf16 8192x512)
        Bt += (size_t)z * 262144 * 4;    // wg_z (f32 512x512)
    }

    f32x4 acc[4][4];
    #pragma unroll
    for (int i = 0; i < 4; ++i)
        #pragma unroll
        for (int j = 0; j < 4; ++j) acc[i][j] = (f32x4){0.f, 0.f, 0.f, 0.f};

    const int sr = tid >> 1, sc = (tid & 1) * 16;   // staging: row, col-half

    for (int kt = 0; kt < nkb; ++kt) {
        const int kb = kt * 32;
        __syncthreads();
        // ---- stage A tile (128 x 32) ----
        if constexpr (A_BF) {
            const bf16* p = (const bf16*)A + (size_t)(m0 + sr) * lda + kb + sc;
            *(s16x8*)&sAh[sr * LS + sc]     = *(const s16x8*)p;
            *(s16x8*)&sAh[sr * LS + sc + 8] = *(const s16x8*)(p + 8);
        } else {
            const float* p = (const float*)A + (size_t)(m0 + sr) * lda + kb + sc;
            s16x8 h0, h1;
            if constexpr (A_SP) {
                s16x8 l0, l1;
                cvt8(p, h0, l0); cvt8(p + 8, h1, l1);
                *(s16x8*)&sAl[sr * LS + sc]     = l0;
                *(s16x8*)&sAl[sr * LS + sc + 8] = l1;
            } else {
                cvt8hi(p, h0); cvt8hi(p + 8, h1);
            }
            *(s16x8*)&sAh[sr * LS + sc]     = h0;
            *(s16x8*)&sAh[sr * LS + sc + 8] = h1;
        }
        // ---- stage B tile (128 x 32) ----
        if constexpr (B_BF) {
            const bf16* p = (const bf16*)Bt + (size_t)(n0 + sr) * ldb + kb + sc;
            *(s16x8*)&sBh[sr * LS + sc]     = *(const s16x8*)p;
            *(s16x8*)&sBh[sr * LS + sc + 8] = *(const s16x8*)(p + 8);
        } else {
            const float* p = (const float*)Bt + (size_t)(n0 + sr) * ldb + kb + sc;
            s16x8 h0, h1, l0, l1;
            cvt8(p, h0, l0); cvt8(p + 8, h1, l1);
            *(s16x8*)&sBh[sr * LS + sc]     = h0;
            *(s16x8*)&sBh[sr * LS + sc + 8] = h1;
            *(s16x8*)&sBl[sr * LS + sc]     = l0;
            *(s16x8*)&sBl[sr * LS + sc + 8] = l1;
        }
        __syncthreads();

        // ---- fragments + MFMA ----
        s16x8 ah[4], al[4], bh[4], bl[4];
        #pragma unroll
        for (int i = 0; i < 4; ++i) {
            const int ra = (wm * 64 + i * 16 + l16) * LS + l4 * 8;
            const int rb = (wn * 64 + i * 16 + l16) * LS + l4 * 8;
            ah[i] = *(const s16x8*)&sAh[ra];
            if constexpr (A_SP) al[i] = *(const s16x8*)&sAl[ra];
            bh[i] = *(const s16x8*)&sBh[rb];
            if constexpr (B_SP) bl[i] = *(const s16x8*)&sBl[rb];
        }
        #pragma unroll
        for (int mi = 0; mi < 4; ++mi)
            #pragma unroll
            for (int ni = 0; ni < 4; ++ni) {
                mfma_bf16(acc[mi][ni], ah[mi], bh[ni]);
                if constexpr (B_SP) mfma_bf16(acc[mi][ni], ah[mi], bl[ni]);
                if constexpr (A_SP) mfma_bf16(acc[mi][ni], al[mi], bh[ni]);
            }
    }

    // ---- epilogues (C frag: row = 4*l4 + r, col = l16) ----
    if constexpr (MODE == 0) {
        float* Q = (float*)Cbase;
        #pragma unroll
        for (int ni = 0; ni < 4; ++ni) {
            const int gn = n0 + wn * 64 + ni * 16 + l16;
            const float bs = bias[gn];
            const int h = gn >> 6, dk = gn & 63;
            #pragma unroll
            for (int mi = 0; mi < 4; ++mi) {
                const int gm0 = m0 + wm * 64 + mi * 16 + l4 * 4;
                const int b = gm0 >> 10, l0 = gm0 & 1023;
                float* dst = Q + (((size_t)(h * 8 + b)) * 1024 + l0) * 64 + dk;
                #pragma unroll
                for (int r = 0; r < 4; ++r) dst[(size_t)r * 64] = acc[mi][ni][r] + bs;
            }
        }
    } else if constexpr (MODE == 1) {
        bf16* Vt = (bf16*)Cbase;
        #pragma unroll
        for (int ni = 0; ni < 4; ++ni) {
            const int gn = n0 + wn * 64 + ni * 16 + l16;
            const float bs = bias[gn];
            const int h = gn >> 9, dv = gn & 511;
            #pragma unroll
            for (int mi = 0; mi < 4; ++mi) {
                const int gm0 = m0 + wm * 64 + mi * 16 + l4 * 4;
                const int b = gm0 >> 10, l0 = gm0 & 1023;
                ushort4 t;
                t.x = f2bfu(acc[mi][ni][0] + bs);
                t.y = f2bfu(acc[mi][ni][1] + bs);
                t.z = f2bfu(acc[mi][ni][2] + bs);
                t.w = f2bfu(acc[mi][ni][3] + bs);
                *(ushort4*)(Vt + ((size_t)(h * 8 + b) * 512 + dv) * 1024 + l0) = t;
            }
        }
    } else if constexpr (MODE == 2) {
        bf16* O = (bf16*)Cbase + (size_t)(aux * 8 + z) * 524288;
        #pragma unroll
        for (int mi = 0; mi < 4; ++mi) {
            const int gm0 = m0 + wm * 64 + mi * 16 + l4 * 4;
            #pragma unroll
            for (int ni = 0; ni < 4; ++ni) {
                const int gn = n0 + wn * 64 + ni * 16 + l16;
                #pragma unroll
                for (int r = 0; r < 4; ++r)
                    O[(size_t)(gm0 + r) * 512 + gn] = f2bf(acc[mi][ni][r]);
            }
        }
    } else if constexpr (MODE == 3) {
        bf16* G = (bf16*)Cbase + (size_t)z * 4194304;
        #pragma unroll
        for (int ni = 0; ni < 4; ++ni) {
            const int gn = n0 + wn * 64 + ni * 16 + l16;
            const float bs = bias[z * 512 + gn];
            #pragma unroll
            for (int mi = 0; mi < 4; ++mi) {
                const int gm0 = m0 + wm * 64 + mi * 16 + l4 * 4;
                #pragma unroll
                for (int r = 0; r < 4; ++r)
                    G[(size_t)(gm0 + r) * 512 + gn] = f2bf(acc[mi][ni][r] + bs);
            }
        }
    } else {
        float* Out = (float*)Cbase;
        #pragma unroll
        for (int mi = 0; mi < 4; ++mi) {
            const int gm0 = m0 + wm * 64 + mi * 16 + l4 * 4;
            const int len = lens[gm0 >> 10];
            #pragma unroll
            for (int ni = 0; ni < 4; ++ni) {
                const int gn = n0 + wn * 64 + ni * 16 + l16;
                const float bs = bias[gn];
                #pragma unroll
                for (int r = 0; r < 4; ++r) {
                    const int gm = gm0 + r;
                    const bool dead = (gm & 1023) >= len;
                    Out[(size_t)gm * 512 + gn] =
                        dead ? 0.f : acc[mi][ni][r] + bs + resid[(size_t)gm * 512 + gn];
                }
            }
        }
    }
}

// ---------------- S = QK^T/8, register-S softmax, P bf16 (zero-padded) -----------------
// Block = (qb: 32 q-rows, z: batch), 512 thr = 8 waves; wave w owns q-rows [4w,4w+4).
// K staged per 128-row chunk in XOR-swizzled LDS; lane covers k = i*64+lane, i in [0,16).
__launch_bounds__(512)
__global__ void k_sattn_lds(const float* __restrict__ Qf, const float* __restrict__ Kf,
                            bf16* __restrict__ P, const int* __restrict__ lens, int head)
{
    __shared__ float sQ[32][64];     // 8 KB
    __shared__ float sK[128 * 64];   // 32 KB, rows XOR-swizzled by (row&15)<<2
    const int qb = blockIdx.x, z = blockIdx.y;      // z = batch
    const int hb = head * 8 + z;
    const int tid = threadIdx.x;

    {   // stage Q tile (32 x 64 f32): 512 threads x f32x4
        const int r = tid >> 4, c0 = (tid & 15) * 4;
        *(f32x4*)&sQ[r][c0] =
            *(const f32x4*)&Qf[((size_t)hb * 1024 + (size_t)qb * 32 + r) * 64 + c0];
    }

    const int w = tid >> 6, lane = tid & 63;
    const float* Kbase = Kf + (size_t)hb * 65536;
    const float* qp = &sQ[w * 4][0];                // wave-uniform row base
    const int swz = (lane & 15) << 2;               // swizzle for rows lane, lane+64

    float s[4][16];                                 // s[q][i] <-> k = i*64 + lane

    for (int kc = 0; kc < 8; ++kc) {
        __syncthreads();             // protect sK overwrite (and first-iter sQ)
        {   // stage K rows [kc*128, kc*128+128): thread t -> row t>>2, 16 cols
            const int r = tid >> 2, c0 = (tid & 3) * 16;
            const float* src = Kbase + (size_t)(kc * 128 + r) * 64 + c0;
            const int sw = (r & 15) << 2;
            #pragma unroll
            for (int c4 = 0; c4 < 4; ++c4)
                *(f32x4*)&sK[r * 64 + ((c0 + c4 * 4) ^ sw)] = *(const f32x4*)(src + c4 * 4);
        }
        __syncthreads();
        float a00 = 0.f, a01 = 0.f, a10 = 0.f, a11 = 0.f,
              a20 = 0.f, a21 = 0.f, a30 = 0.f, a31 = 0.f;
        #pragma unroll
        for (int j = 0; j < 16; ++j) {
            const int cs = (j * 4) ^ swz;
            const f32x4 k0 = *(const f32x4*)&sK[lane * 64 + cs];
            const f32x4 k1 = *(const f32x4*)&sK[(lane + 64) * 64 + cs];
            const f32x4 q0 = *(const f32x4*)(qp + 0 * 64 + j * 4);
            const f32x4 q1 = *(const f32x4*)(qp + 1 * 64 + j * 4);
            const f32x4 q2 = *(const f32x4*)(qp + 2 * 64 + j * 4);
            const f32x4 q3 = *(const f32x4*)(qp + 3 * 64 + j * 4);
            a00 += q0[0]*k0[0] + q0[1]*k0[1] + q0[2]*k0[2] + q0[3]*k0[3];
            a01 += q0[0]*k1[0] + q0[1]*k1[1] + q0[2]*k1[2] + q0[3]*k1[3];
            a10 += q1[0]*k0[0] + q1[1]*k0[1] + q1[2]*k0[2] + q1[3]*k0[3];
            a11 += q1[0]*k1[0] + q1[1]*k1[1] + q1[2]*k1[2] + q1[3]*k1[3];
            a20 += q2[0]*k0[0] + q2[1]*k0[1] + q2[2]*k0[2] + q2[3]*k0[3];
            a21 += q2[0]*k1[0] + q2[1]*k1[1] + q2[2]*k1[2] + q2[3]*k1[3];
            a30 += q3[0]*k0[0] + q3[1]*k0[1] + q3[2]*k0[2] + q3[3]*k0[3];
            a31 += q3[0]*k1[0] + q3[1]*k1[1] + q3[2]*k1[2] + q3[3]*k1[3];
        }
        s[0][kc * 2] = a00 * 0.125f;  s[0][kc * 2 + 1] = a01 * 0.125f;
        s[1][kc * 2] = a10 * 0.125f;  s[1][kc * 2 + 1] = a11 * 0.125f;
        s[2][kc * 2] = a20 * 0.125f;  s[2][kc * 2 + 1] = a21 * 0.125f;
        s[3][kc * 2] = a30 * 0.125f;  s[3][kc * 2 + 1] = a31 * 0.125f;
    }
    // note: s[q][i] with k = (i>>1)*128 + (i&1)*64 + lane == i*64 + lane  (same as r8)

    const int len = lens[z], lenpad = lens[8 + z] * 32;
    #pragma unroll
    for (int q = 0; q < 4; ++q) {
        float mx = -3.0e38f;
        #pragma unroll
        for (int i = 0; i < 16; ++i)
            if (i * 64 + lane < len) mx = fmaxf(mx, s[q][i]);
        #pragma unroll
        for (int off = 32; off; off >>= 1) mx = fmaxf(mx, __shfl_xor(mx, off));
        float sum = 0.f;
        #pragma unroll
        for (int i = 0; i < 16; ++i) {
            const float e = (i * 64 + lane < len) ? __expf(s[q][i] - mx) : 0.f;
            s[q][i] = e;
            sum += e;
        }
        #pragma unroll
        for (int off = 32; off; off >>= 1) sum += __shfl_xor(sum, off);
        const float rinv = 1.0f / sum;
        bf16* Pr = P + ((size_t)z * 1024 + (size_t)qb * 32 + w * 4 + q) * 1024;
        #pragma unroll
        for (int i = 0; i < 16; ++i) {
            const int k = i * 64 + lane;
            if (k < lenpad) Pr[k] = f2bf(s[q][i] * rinv);
        }
    }
}

// ---------------- head-softmax gate combine: comb = sum_h softmax_h(G) * O -------------
__launch_bounds__(512)
__global__ void k_combine_f32(const bf16* __restrict__ G, const bf16* __restrict__ O,
                              float* __restrict__ comb)
{
    const size_t row = blockIdx.x;
    const int e = threadIdx.x;
    const size_t idx = row * 512 + e;
    float g[8];
    #pragma unroll
    for (int h = 0; h < 8; ++h) g[h] = bf2f(G[(size_t)h * 4194304 + idx]);
    float mx = g[0];
    #pragma unroll
    for (int h = 1; h < 8; ++h) mx = fmaxf(mx, g[h]);
    float s = 0.f, c = 0.f;
    #pragma unroll
    for (int h = 0; h < 8; ++h) {
        const float p = __expf(g[h] - mx);
        s += p;
        c += p * bf2f(O[(size_t)h * 4194304 + idx]);
    }
    comb[idx] = c / s;
}

__global__ void k_sentinel(float* out, int n) {
    const int i = blockIdx.x * 256 + threadIdx.x;
    if (i < n) out[i] = 12345.0f;
}

// ---------------------------------------------------------------------------------------
extern "C" void kernel_launch(void* const* d_in, const int* in_sizes, int n_in,
                              void* d_out, int out_size, void* d_ws, size_t ws_size,
                              hipStream_t stream)
{
    const float* enc = (const float*)d_in[0];
    const unsigned char* npm = (const unsigned char*)d_in[1];
    const float* wq  = (const float*)d_in[3];
    const float* bq  = (const float*)d_in[4];
    const float* wk  = (const float*)d_in[5];
    const float* bk  = (const float*)d_in[6];
    const float* wv  = (const float*)d_in[7];
    const float* bv  = (const float*)d_in[8];
    const float* wg  = (const float*)d_in[9];
    const float* bg  = (const float*)d_in[10];
    const float* wfc = (const float*)d_in[11];
    const float* bfc = (const float*)d_in[12];

    char* ws = (char*)d_ws;
    size_t o = 0;
    auto take = [&](size_t bytes) { char* p = ws + o; o += (bytes + 255) & ~(size_t)255; return p; };
    int*   lens = (int*)take(128);
    float* Qf   = (float*)take((size_t)4194304 * 4);   // [h][b][l][dk] f32
    float* Kf   = (float*)take((size_t)4194304 * 4);   // [h][b][l][dk] f32
    bf16*  Vt   = (bf16*)take((size_t)33554432 * 2);   // [h][b][dv][l] bf16; reused as G
    bf16*  Ob   = (bf16*)take((size_t)33554432 * 2);   // [h][b][l][dv] bf16
    bf16*  Pf   = (bf16*)take((size_t)8388608 * 2);    // one head: [b][q][k] bf16
    float* comb = (float*)take((size_t)4194304 * 4);   // [b,l][dv] f32
    bf16*  Gb   = Vt;

    if (ws_size < o) {
        k_sentinel<<<dim3((out_size + 255) / 256), 256, 0, stream>>>((float*)d_out, out_size);
        return;
    }

    k_lengths<<<1, 256, 0, stream>>>(npm, lens);

    // Q, K projections (MFMA, split-bf16 3-term); V projection (2-term)
    mgemm<0><<<dim3(64 * 4, 1), 256, 0, stream>>>(enc, wq, Qf, bq, nullptr, lens, 4, 0);
    mgemm<0><<<dim3(64 * 4, 1), 256, 0, stream>>>(enc, wk, Kf, bk, nullptr, lens, 4, 0);
    mgemm<1><<<dim3(64 * 32, 1), 256, 0, stream>>>(enc, wv, Vt, bv, nullptr, lens, 32, 0);

    // attention per head: register-S softmax -> P (bf16), then MFMA PV -> O
    for (int g = 0; g < 8; ++g) {
        k_sattn_lds<<<dim3(32, 8), 512, 0, stream>>>(Qf, Kf, Pf, lens, g);
        mgemm<2><<<dim3(8 * 4, 8), 256, 0, stream>>>(Pf, Vt + (size_t)g * 4194304, Ob,
                                                     nullptr, nullptr, lens, 4, g);
    }

    // gate GEMM per head (MFMA, A bf16-native, B split 2-term)
    mgemm<3><<<dim3(64 * 4, 8), 256, 0, stream>>>(Ob, wg, Gb, bg, nullptr, lens, 4, 0);

    // head softmax + weighted combine
    k_combine_f32<<<dim3(8192), 512, 0, stream>>>(Gb, Ob, comb);

    // FC + bias + residual + pad-mask -> f32 out
    mgemm<4><<<dim3(64 * 4, 1), 256, 0, stream>>>(comb, wfc, d_out, bfc, enc, lens, 4, 0);
}